// Round 1
// baseline (365.032 us; speedup 1.0000x reference)
//
#include <hip/hip_runtime.h>
#include <math.h>

// FLIFP: fractional LIF forward.
// I: [B=8, T=1024, L=1024] f32. Outputs: spikes [B,T,L], voltage [B,T,L], concatenated.
// memory kernel wm(m) = (m+2)^0.8 - (m+1)^0.8 approximated as sum of K exponentials
// via exp-sinh (DE) quadrature of wm(m) = (0.8/Gamma(0.2)) \int s^{-1.8} e^{-ms}(e^{-s}-e^{-2s}) ds.

#define K_EXP 32
#define T_STEPS 1024
#define L_DIM 1024
#define B_DIM 8

struct Coefs {
    float rho[K_EXP];   // rho_k = exp(-s_k)
    float arho[K_EXP];  // A_k * rho_k
};

__global__ __launch_bounds__(64) void flifp_kernel(
    const float* __restrict__ I,
    float* __restrict__ spk,
    float* __restrict__ vout,
    Coefs c, float coef)
{
    const int neuron = blockIdx.x * 64 + threadIdx.x;  // 0 .. 8191
    const int b = neuron >> 10;          // / L_DIM
    const int l = neuron & (L_DIM - 1);
    const size_t base = ((size_t)b << 20) + (size_t)l;  // b*T*L + l
    const float* Ip = I + base;
    float* sp = spk + base;
    float* vp = vout + base;

    const float THR = -50.0f;
    const float VINIT = -70.0f;
    const float VL = -70.0f;
    const float GL = 0.025f;

    // t = 0
    sp[0] = 0.0f;           // V0 = -70 < -50
    vp[0] = VINIT;

    // t = 1: V1 = V0 + (DT/TAU)*(-V0 + I0/GL), DT/TAU = 0.005, 1/GL = 40
    float I0 = Ip[0];
    float V = VINIT + 0.005f * (-VINIT + I0 * 40.0f);
    sp[(size_t)1 << 10] = (V - THR > 0.0f) ? 1.0f : 0.0f;
    vp[(size_t)1 << 10] = V;

    // d1 = V1 - V0 (pre-reset delta; V1 has no reset)
    float d = V - VINIT;

    // q_k(N) = sum_{j<=N-1} rho^{N-1-j} d_j ; init q_k = d1 (N=2)
    float q[K_EXP];
#pragma unroll
    for (int k = 0; k < K_EXP; ++k) q[k] = d;

    for (int t = 2; t < T_STEPS; ++t) {
        float In = Ip[(size_t)t << 10];

        // memory_V(N) = sum_k (A_k rho_k) q_k
        float m0 = 0.0f, m1 = 0.0f, m2 = 0.0f, m3 = 0.0f;
#pragma unroll
        for (int k = 0; k < K_EXP; k += 4) {
            m0 = fmaf(c.arho[k + 0], q[k + 0], m0);
            m1 = fmaf(c.arho[k + 1], q[k + 1], m1);
            m2 = fmaf(c.arho[k + 2], q[k + 2], m2);
            m3 = fmaf(c.arho[k + 3], q[k + 3], m3);
        }
        float mem = (m0 + m1) + (m2 + m3);

        float gate20 = (V - THR > 0.0f) ? 20.0f : 0.0f;   // gate on V_old
        float Vpre = fmaf(coef, fmaf(-GL, V - VL, In), V) - mem;
        d = Vpre - V;            // hist delta: pre-reset new minus post-reset old
        V = Vpre - gate20;       // reset

        sp[(size_t)t << 10] = (V - THR > 0.0f) ? 1.0f : 0.0f;
        vp[(size_t)t << 10] = V;

        // q_k <- rho_k*q_k + d
#pragma unroll
        for (int k = 0; k < K_EXP; ++k) q[k] = fmaf(c.rho[k], q[k], d);
    }
}

static void make_coefs(Coefs* c, float* coef_out)
{
    const double Cc = 0.8 / tgamma(0.2);     // 0.8 / Gamma(0.2)
    const double delta = 0.25;
    const double x0 = -4.25;                 // 32 nodes: x in [-4.25, 3.5]
    for (int k = 0; k < K_EXP; ++k) {
        double x = x0 + delta * (double)k;
        double s = exp(x - exp(-x));         // exp-sinh node
        // e^{-s} - e^{-2s} = e^{-s} * (1 - e^{-s}) = e^{-s} * (-expm1(-s))  (stable for tiny s)
        double em = exp(-s);
        double diff = em * (-expm1(-s));
        double A = Cc * delta * pow(s, -1.8) * diff * s * (1.0 + exp(-x)); // s^{-1.8}*diff * ds/dx; ds/dx = s*(1+e^{-x})
        double rho = em;
        c->rho[k]  = (float)rho;
        c->arho[k] = (float)(A * rho);
    }
    // coef = DT^alpha * Gamma(2-alpha) / CM
    *coef_out = (float)(pow(0.1, 0.2) * tgamma(1.8) / 0.5);
}

extern "C" void kernel_launch(void* const* d_in, const int* in_sizes, int n_in,
                              void* d_out, int out_size, void* d_ws, size_t ws_size,
                              hipStream_t stream)
{
    (void)in_sizes; (void)n_in; (void)d_ws; (void)ws_size;

    const float* I = (const float*)d_in[0];
    float* out0 = (float*)d_out;                                   // spikes [B,T,L]
    float* out1 = out0 + (size_t)B_DIM * T_STEPS * L_DIM;          // voltage [B,T,L]

    Coefs c;
    float coef;
    make_coefs(&c, &coef);

    const int neurons = B_DIM * L_DIM;      // 8192
    flifp_kernel<<<neurons / 64, 64, 0, stream>>>(I, out0, out1, c, coef);
}

// Round 2
// 128.721 us; speedup vs baseline: 2.8358x; 2.8358x over previous
//
#include <hip/hip_runtime.h>
#include <math.h>

// FLIFP: fractional LIF forward.
// I: [B=8, T=1024, L=1024] f32. Outputs: spikes [B,T,L], voltage [B,T,L], concatenated.
// memory kernel wm(m) = (m+2)^0.8 - (m+1)^0.8 approximated as sum of K exponentials
// via exp-sinh (DE) quadrature; per-step cost O(K) via one-pole recurrences.
// R2: software-pipelined I loads (prefetch distance 8) — R1 was latency-bound on
// the per-step global load (1 wave/SIMD, no TLP to hide ~700cy HBM latency).

#define K_EXP 32
#define T_STEPS 1024
#define L_DIM 1024
#define B_DIM 8
#define PF 8

struct Coefs {
    float rho[K_EXP];   // rho_k = exp(-s_k)
    float arho[K_EXP];  // A_k * rho_k
};

__global__ __launch_bounds__(64) void flifp_kernel(
    const float* __restrict__ I,
    float* __restrict__ spk,
    float* __restrict__ vout,
    Coefs c, float coef)
{
    const int neuron = blockIdx.x * 64 + threadIdx.x;  // 0 .. 8191
    const int b = neuron >> 10;          // / L_DIM
    const int l = neuron & (L_DIM - 1);
    const size_t base = ((size_t)b << 20) + (size_t)l;  // b*T*L + l
    const float* Ip = I + base;
    float* sp = spk + base;
    float* vp = vout + base;

    const float THR = -50.0f;
    const float VINIT = -70.0f;
    const float VL = -70.0f;
    const float GL = 0.025f;

    // t = 0
    sp[0] = 0.0f;           // V0 = -70 < -50
    vp[0] = VINIT;

    // t = 1: V1 = V0 + (DT/TAU)*(-V0 + I0/GL), DT/TAU = 0.005, 1/GL = 40
    float I0 = Ip[0];
    float V = VINIT + 0.005f * (-VINIT + I0 * 40.0f);
    sp[(size_t)1 << 10] = (V - THR > 0.0f) ? 1.0f : 0.0f;
    vp[(size_t)1 << 10] = V;

    // d1 = V1 - V0 (pre-reset delta; V1 has no reset)
    float d = V - VINIT;

    // q_k(N) = sum_{j<=N-1} rho^{N-1-j} d_j ; init q_k = d1 (N=2)
    float q[K_EXP];
#pragma unroll
    for (int k = 0; k < K_EXP; ++k) q[k] = d;

    auto step = [&](int t, float In) {
        // memory_V = sum_k (A_k rho_k) q_k
        float m0 = 0.0f, m1 = 0.0f, m2 = 0.0f, m3 = 0.0f;
#pragma unroll
        for (int k = 0; k < K_EXP; k += 4) {
            m0 = fmaf(c.arho[k + 0], q[k + 0], m0);
            m1 = fmaf(c.arho[k + 1], q[k + 1], m1);
            m2 = fmaf(c.arho[k + 2], q[k + 2], m2);
            m3 = fmaf(c.arho[k + 3], q[k + 3], m3);
        }
        float mem = (m0 + m1) + (m2 + m3);

        float gate20 = (V - THR > 0.0f) ? 20.0f : 0.0f;   // gate on V_old
        float Vpre = fmaf(coef, fmaf(-GL, V - VL, In), V) - mem;
        d = Vpre - V;            // hist delta: pre-reset new minus post-reset old
        V = Vpre - gate20;       // reset

        sp[(size_t)t << 10] = (V - THR > 0.0f) ? 1.0f : 0.0f;
        vp[(size_t)t << 10] = V;

        // q_k <- rho_k*q_k + d
#pragma unroll
        for (int k = 0; k < K_EXP; ++k) q[k] = fmaf(c.rho[k], q[k], d);
    };

    // prefetch first batch (t = 2..9)
    float Ibuf[PF];
#pragma unroll
    for (int i = 0; i < PF; ++i) Ibuf[i] = Ip[(size_t)(2 + i) << 10];

    // main loop: 127 batches of 8 steps (t = 2 .. 1017), prefetching 8 ahead
    for (int t0 = 2; t0 + PF <= T_STEPS; t0 += PF) {
        float Inext[PF];
        const int tn = t0 + PF;
#pragma unroll
        for (int i = 0; i < PF; ++i) {
            int tc = tn + i;
            tc = (tc < T_STEPS) ? tc : (T_STEPS - 1);   // clamp: keep address valid
            Inext[i] = Ip[(size_t)tc << 10];
        }
#pragma unroll
        for (int i = 0; i < PF; ++i) step(t0 + i, Ibuf[i]);
#pragma unroll
        for (int i = 0; i < PF; ++i) Ibuf[i] = Inext[i];
    }

    // tail: t = 1018..1023 (values already prefetched in last main iteration)
#pragma unroll
    for (int i = 0; i < 6; ++i) step(1018 + i, Ibuf[i]);
}

static void make_coefs(Coefs* c, float* coef_out)
{
    const double Cc = 0.8 / tgamma(0.2);     // 0.8 / Gamma(0.2)
    const double delta = 0.25;
    const double x0 = -4.25;                 // 32 nodes: x in [-4.25, 3.5]
    for (int k = 0; k < K_EXP; ++k) {
        double x = x0 + delta * (double)k;
        double s = exp(x - exp(-x));         // exp-sinh node
        double em = exp(-s);
        double diff = em * (-expm1(-s));     // e^{-s} - e^{-2s}, stable for tiny s
        double A = Cc * delta * pow(s, -1.8) * diff * s * (1.0 + exp(-x)); // weight * ds/dx
        c->rho[k]  = (float)em;
        c->arho[k] = (float)(A * em);
    }
    // coef = DT^alpha * Gamma(2-alpha) / CM
    *coef_out = (float)(pow(0.1, 0.2) * tgamma(1.8) / 0.5);
}

extern "C" void kernel_launch(void* const* d_in, const int* in_sizes, int n_in,
                              void* d_out, int out_size, void* d_ws, size_t ws_size,
                              hipStream_t stream)
{
    (void)in_sizes; (void)n_in; (void)d_ws; (void)ws_size;

    const float* I = (const float*)d_in[0];
    float* out0 = (float*)d_out;                                   // spikes [B,T,L]
    float* out1 = out0 + (size_t)B_DIM * T_STEPS * L_DIM;          // voltage [B,T,L]

    Coefs c;
    float coef;
    make_coefs(&c, &coef);

    const int neurons = B_DIM * L_DIM;      // 8192
    flifp_kernel<<<neurons / 64, 64, 0, stream>>>(I, out0, out1, c, coef);
}